// Round 5
// baseline (482.664 us; speedup 1.0000x reference)
//
#include <hip/hip_runtime.h>

#define FEAT 256
#define EMB 256

typedef __attribute__((ext_vector_type(4))) float f32x4;
typedef __attribute__((ext_vector_type(8))) short short8;

// packed fp32x2 -> bf16x2 (RNE) in one instruction
__device__ __forceinline__ unsigned cvtpk(float lo, float hi) {
    unsigned r;
    asm volatile("v_cvt_pk_bf16_f32 %0, %1, %2" : "=v"(r) : "v"(lo), "v"(hi));
    return r;
}

// h = X @ W^T quantized to int8 (biased-u8), stored in LINEAR byte layout:
// H byte (row*256 + c) = col c of row. Linear layout lets the SpMM slice the
// row into 8x32B column-slices (one per XCD, L2-resident). Repack from the
// MFMA dword layout (lane cc holds cols {b*64+16j+cc}, j=0..3 packed) to
// linear (lane w holds cols b*64+4w..4w+3) is a 4x4 byte transpose among
// lanes 4*(w&3)+{0..3} via a per-wave-private LDS bounce (no barrier).
// S stored as planes S[b][row] so the SpMM's XCD touches only its plane.
// GEMM pipeline = round-3 proven form: register prefetch, 2 barriers/step
// (dbuf and async variants measured worse).
__global__ __launch_bounds__(512) void gemm_q8(
    const float* __restrict__ X, const float* __restrict__ W,
    unsigned* __restrict__ H32, float* __restrict__ S, int M) {
    __shared__ ushort As[128][32];
    __shared__ ushort Bs[256][32];
    __shared__ unsigned lbuf[512];   // epilogue repack bounce (per-thread slot)

    const int t    = threadIdx.x;
    const int lane = t & 63;
    const int wave = t >> 6;
    const int wr   = (wave >> 2) * 64;   // 0 or 64
    const int wc   = (wave & 3) * 64;    // 0,64,128,192
    const int m0   = blockIdx.x * 128;

    f32x4 acc[4][4] = {};

    const int srow = t >> 3;          // 0..63
    const int sc4  = (t & 7) * 4;     // col 0,4,...,28
    const int gr0  = m0 + srow;
    const int gr1  = m0 + srow + 64;
    const float* const xp0 = X + (size_t)gr0 * FEAT + sc4;
    const float* const xp1 = X + (size_t)gr1 * FEAT + sc4;
    const float* const wp  = W + (size_t)srow * FEAT + sc4;

    // prologue: load step 0
    f32x4 xv0 = {0.f, 0.f, 0.f, 0.f}, xv1 = {0.f, 0.f, 0.f, 0.f};
    f32x4 wv[4];
    if (gr0 < M) xv0 = *(const f32x4*)xp0;
    if (gr1 < M) xv1 = *(const f32x4*)xp1;
    #pragma unroll
    for (int j = 0; j < 4; ++j) wv[j] = *(const f32x4*)(wp + (size_t)j * 64 * FEAT);

    for (int k0 = 0; k0 < FEAT; k0 += 32) {
        __syncthreads();   // prev step's ds_reads done; LDS reusable
        {
            uint2 u0 = {cvtpk(xv0.x, xv0.y), cvtpk(xv0.z, xv0.w)};
            uint2 u1 = {cvtpk(xv1.x, xv1.y), cvtpk(xv1.z, xv1.w)};
            *(uint2*)&As[srow][sc4]      = u0;
            *(uint2*)&As[srow + 64][sc4] = u1;
            #pragma unroll
            for (int j = 0; j < 4; ++j) {
                uint2 uw = {cvtpk(wv[j].x, wv[j].y), cvtpk(wv[j].z, wv[j].w)};
                *(uint2*)&Bs[srow + 64 * j][sc4] = uw;
            }
        }
        __syncthreads();

        // issue next step's loads now; they drain at the NEXT LDS write
        if (k0 + 32 < FEAT) {
            const int kn = k0 + 32;
            xv0 = {0.f, 0.f, 0.f, 0.f};
            xv1 = {0.f, 0.f, 0.f, 0.f};
            if (gr0 < M) xv0 = *(const f32x4*)(xp0 + kn);
            if (gr1 < M) xv1 = *(const f32x4*)(xp1 + kn);
            #pragma unroll
            for (int j = 0; j < 4; ++j)
                wv[j] = *(const f32x4*)(wp + (size_t)j * 64 * FEAT + kn);
        }

        const int r  = lane & 15;
        const int kr = (lane >> 4) * 8;
        short8 a[4], b[4];
        #pragma unroll
        for (int i = 0; i < 4; ++i) a[i] = *(const short8*)&As[wr + i * 16 + r][kr];
        #pragma unroll
        for (int j = 0; j < 4; ++j) b[j] = *(const short8*)&Bs[wc + j * 16 + r][kr];
        #pragma unroll
        for (int i = 0; i < 4; ++i)
            #pragma unroll
            for (int j = 0; j < 4; ++j)
                acc[i][j] = __builtin_amdgcn_mfma_f32_16x16x32_bf16(a[i], b[j], acc[i][j], 0, 0, 0);
    }

    // epilogue: C/D mapping col = wc + j*16 + (lane&15), row = wr + i*16 + (lane>>4)*4 + q.
    const int g  = lane >> 4;
    const int cc = lane & 15;
    const int b  = wave & 3;          // 64-col block index (= wc/64)
    const int sel  = cc >> 2;         // byte index for repack
    const int rbase = wave * 64 + g * 16 + 4 * (cc & 3);
    #pragma unroll
    for (int i = 0; i < 4; ++i) {
        #pragma unroll
        for (int q = 0; q < 4; ++q) {
            const int row = m0 + wr + i * 16 + g * 4 + q;
            float mx = fmaxf(fmaxf(fabsf(acc[i][0][q]), fabsf(acc[i][1][q])),
                             fmaxf(fabsf(acc[i][2][q]), fabsf(acc[i][3][q])));
            mx = fmaxf(mx, __shfl_xor(mx, 1, 64));
            mx = fmaxf(mx, __shfl_xor(mx, 2, 64));
            mx = fmaxf(mx, __shfl_xor(mx, 4, 64));
            mx = fmaxf(mx, __shfl_xor(mx, 8, 64));
            const float inv = mx > 1e-30f ? 127.0f * __builtin_amdgcn_rcpf(mx) : 0.0f;
            unsigned wdw = 0;
            #pragma unroll
            for (int j = 0; j < 4; ++j) {
                int u = (int)fmaf(acc[i][j][q], inv, 128.5f);
                u = u < 0 ? 0 : (u > 255 ? 255 : u);
                wdw |= (unsigned)u << (8 * j);
            }
            // repack: lane (as w=cc) takes byte 'sel' of lanes 4*(cc&3)+{0..3}
            lbuf[t] = wdw;                       // ds_write (per-wave-private)
            uint4 d = *(const uint4*)&lbuf[rbase];  // ds_read_b128 (same wave)
            unsigned o = ((d.x >> (8 * sel)) & 0xffu)
                       | (((d.y >> (8 * sel)) & 0xffu) << 8)
                       | (((d.z >> (8 * sel)) & 0xffu) << 16)
                       | (((d.w >> (8 * sel)) & 0xffu) << 24);
            if (row < M) {
                H32[(size_t)row * 64 + b * 16 + cc] = o;  // linear: dword w=cc of block b
                if (cc == 0) S[(size_t)b * M + row] = mx * (1.0f / 127.0f);
            }
        }
    }
}

// edge_dst is sorted: rp[n] = first edge with dst >= n; rp[N] = E.
__global__ __launch_bounds__(256) void build_rowptr(
    const int* __restrict__ dst, int* __restrict__ rp, int E, int N) {
    int e = blockIdx.x * 256 + threadIdx.x;
    if (e >= E) return;
    int d    = dst[e];
    int prev = (e == 0) ? -1 : dst[e - 1];
    for (int n = prev + 1; n <= d; ++n) rp[n] = e;
    if (e == E - 1) {
        for (int n = d + 1; n <= N; ++n) rp[n] = E;
    }
}

// Column-sliced SpMM: slice s = 32B of each H row (cols s*32..s*32+31),
// pinned to XCD s via blockIdx&7 (HW round-robins consecutive blocks across
// XCDs). Per-XCD gather working set = 3.2MB slice + 0.4MB S-plane -> L2
// resident; the 228MB random-gather HBM wall becomes L2 hits. 8 lanes/node,
// lane owns 4 contiguous cols (1 dword); 32 nodes/block. Edge lists re-read
// once per slice (8x, +90MB HBM, streamed via NT loads to spare L2).
// Dequant bias-correction: out = sum(vs*u) - 128*sum(vs). NT stores.
__global__ __launch_bounds__(256) void spmm_q8(
    const unsigned* __restrict__ H32, const float* __restrict__ S,
    const int* __restrict__ rp, const int* __restrict__ src,
    const float* __restrict__ val, float* __restrict__ out, int M) {
    const int t     = threadIdx.x;
    const int li    = t & 7;             // lane within group
    const int grp   = t >> 3;            // group 0..31 (one node each)
    const int slice = blockIdx.x & 7;    // -> XCD slice&7
    const int node  = (blockIdx.x >> 3) * 32 + grp;
    if (node >= M) return;
    const float* const Sb = S + (size_t)(slice >> 1) * M;  // scale plane for this slice
    const int doff = slice * 8 + li;     // dword index within 64-dword row
    const int lo = rp[node], hi = rp[node + 1];

    float a0[4] = {0.f, 0.f, 0.f, 0.f}, a1[4] = {0.f, 0.f, 0.f, 0.f};
    float c0 = 0.f, c1 = 0.f;

    for (int e = lo; e < hi; e += 2) {
        const int e1 = e + 1;
        const int k1 = e1 < hi ? e1 : e;
        const int s0 = __builtin_nontemporal_load(src + e);
        const int s1 = __builtin_nontemporal_load(src + k1);
        const float v0 = __builtin_nontemporal_load(val + e);
        const float v1 = e1 < hi ? __builtin_nontemporal_load(val + k1) : 0.f;
        const float vs0 = v0 * Sb[s0];
        const float vs1 = v1 * Sb[s1];
        const unsigned p0 = H32[(size_t)s0 * 64 + doff];   // L2-hit gather (4B;
        const unsigned p1 = H32[(size_t)s1 * 64 + doff];   // 8 lanes merge to 32B)
        c0 += vs0;
        c1 += vs1;
        #pragma unroll
        for (int j = 0; j < 4; ++j) {
            a0[j] += vs0 * (float)((p0 >> (8 * j)) & 0xffu);
            a1[j] += vs1 * (float)((p1 >> (8 * j)) & 0xffu);
        }
    }

    const float corr = (c0 + c1) * 128.0f;
    f32x4 o = {a0[0] + a1[0] - corr, a0[1] + a1[1] - corr,
               a0[2] + a1[2] - corr, a0[3] + a1[3] - corr};
    // lane's 4 cols are contiguous: out row byte offset = slice*128 + li*16
    __builtin_nontemporal_store(o, (f32x4*)(out + (size_t)node * EMB + doff * 4));
}

extern "C" void kernel_launch(void* const* d_in, const int* in_sizes, int n_in,
                              void* d_out, int out_size, void* d_ws, size_t ws_size,
                              hipStream_t stream) {
    const float* x    = (const float*)d_in[0];
    const float* w    = (const float*)d_in[1];
    const int*   esrc = (const int*)d_in[2];
    const int*   edst = (const int*)d_in[3];
    const float* eval = (const float*)d_in[4];

    const int M = in_sizes[0] / FEAT;   // 100000
    const int E = in_sizes[2];          // 1600000

    unsigned* Hbuf = (unsigned*)d_ws;                               // [M][64] dwords (linear int8 rows)
    float*    S    = (float*)((char*)d_ws + (size_t)M * 256);       // [4][M] scale planes
    int*      rp   = (int*)((char*)S + (size_t)M * 4 * sizeof(float));

    gemm_q8<<<(M + 127) / 128, 512, 0, stream>>>(x, w, Hbuf, S, M);
    build_rowptr<<<(E + 255) / 256, 256, 0, stream>>>(edst, rp, E, M);
    const int nb = (M + 31) / 32;
    spmm_q8<<<nb * 8, 256, 0, stream>>>(Hbuf, S, rp, esrc, eval, (float*)d_out, M);
}

// Round 6
// 134.295 us; speedup vs baseline: 3.5941x; 3.5941x over previous
//
#include <hip/hip_runtime.h>

#define FEAT 256
#define EMB 256

typedef __attribute__((ext_vector_type(4))) float f32x4;
typedef __attribute__((ext_vector_type(8))) short short8;

// packed fp32x2 -> bf16x2 (RNE) in one instruction
__device__ __forceinline__ unsigned cvtpk(float lo, float hi) {
    unsigned r;
    asm volatile("v_cvt_pk_bf16_f32 %0, %1, %2" : "=v"(r) : "v"(lo), "v"(hi));
    return r;
}

// h = X @ W^T quantized to int8 (biased-u8). H layout: row-major 256B rows,
// within-row byte order [blk(4)][cc(16)][j(4)] so dword (blk*16+cc) holds the
// 4 j-values (cols blk*64 + j*16 + cc) of MFMA lane cc -> single dword store.
// S[row][blk] = per-(row, 64-col block) dequant scale (wave-local absmax).
// Pipeline: round-3 proven 2-barrier skeleton + 2-DEEP register prefetch
// (named A/B sets, static indexing): step k stages set[k%2] whose loads were
// issued at step k-2 -> the vmcnt wait at each cvt is covered by ~2 full
// steps (~2x MFMA+stage phases) instead of one MFMA phase. Ledger: 1-deep
// prefetch 50->34us WIN; dbuf single-barrier REGRESSED (serialized
// MFMA->wait->write); async global_load_lds REGRESSED.
__global__ __launch_bounds__(512) void gemm_q8(
    const float* __restrict__ X, const float* __restrict__ W,
    unsigned* __restrict__ H32, float* __restrict__ S, int M) {
    __shared__ ushort As[128][32];
    __shared__ ushort Bs[256][32];

    const int t    = threadIdx.x;
    const int lane = t & 63;
    const int wave = t >> 6;
    const int wr   = (wave >> 2) * 64;   // 0 or 64
    const int wc   = (wave & 3) * 64;    // 0,64,128,192
    const int m0   = blockIdx.x * 128;

    f32x4 acc[4][4] = {};

    const int srow = t >> 3;          // 0..63
    const int sc4  = (t & 7) * 4;     // col 0,4,...,28
    const int gr0  = m0 + srow;
    const int gr1  = m0 + srow + 64;
    const bool in0 = gr0 < M;
    const bool in1 = gr1 < M;
    const float* const xp0 = X + (size_t)gr0 * FEAT + sc4;
    const float* const xp1 = X + (size_t)gr1 * FEAT + sc4;
    const float* const wp  = W + (size_t)srow * FEAT + sc4;

    const int r  = lane & 15;
    const int kr = (lane >> 4) * 8;

    // two named prefetch sets (static indexing; no runtime-indexed arrays)
    f32x4 xa0 = {0,0,0,0}, xa1 = {0,0,0,0}, wa0, wa1, wa2, wa3;
    f32x4 xb0 = {0,0,0,0}, xb1 = {0,0,0,0}, wb0, wb1, wb2, wb3;

    // prologue: A <- k=0, B <- k=32
    if (in0) xa0 = *(const f32x4*)xp0;
    if (in1) xa1 = *(const f32x4*)xp1;
    wa0 = *(const f32x4*)(wp);
    wa1 = *(const f32x4*)(wp + (size_t)64 * FEAT);
    wa2 = *(const f32x4*)(wp + (size_t)128 * FEAT);
    wa3 = *(const f32x4*)(wp + (size_t)192 * FEAT);
    if (in0) xb0 = *(const f32x4*)(xp0 + 32);
    if (in1) xb1 = *(const f32x4*)(xp1 + 32);
    wb0 = *(const f32x4*)(wp + 32);
    wb1 = *(const f32x4*)(wp + (size_t)64 * FEAT + 32);
    wb2 = *(const f32x4*)(wp + (size_t)128 * FEAT + 32);
    wb3 = *(const f32x4*)(wp + (size_t)192 * FEAT + 32);

    #pragma unroll
    for (int k0 = 0; k0 < FEAT; k0 += 64) {
        // ---- substep A: stage k0 from set A ----
        __syncthreads();
        {
            uint2 u0 = {cvtpk(xa0.x, xa0.y), cvtpk(xa0.z, xa0.w)};
            uint2 u1 = {cvtpk(xa1.x, xa1.y), cvtpk(xa1.z, xa1.w)};
            *(uint2*)&As[srow][sc4]      = u0;
            *(uint2*)&As[srow + 64][sc4] = u1;
            uint2 w0 = {cvtpk(wa0.x, wa0.y), cvtpk(wa0.z, wa0.w)};
            uint2 w1 = {cvtpk(wa1.x, wa1.y), cvtpk(wa1.z, wa1.w)};
            uint2 w2 = {cvtpk(wa2.x, wa2.y), cvtpk(wa2.z, wa2.w)};
            uint2 w3 = {cvtpk(wa3.x, wa3.y), cvtpk(wa3.z, wa3.w)};
            *(uint2*)&Bs[srow][sc4]       = w0;
            *(uint2*)&Bs[srow + 64][sc4]  = w1;
            *(uint2*)&Bs[srow + 128][sc4] = w2;
            *(uint2*)&Bs[srow + 192][sc4] = w3;
        }
        __syncthreads();
        if (k0 + 64 < FEAT) {           // issue A <- k0+64 (2 steps ahead)
            const int kn = k0 + 64;
            xa0 = {0,0,0,0}; xa1 = {0,0,0,0};
            if (in0) xa0 = *(const f32x4*)(xp0 + kn);
            if (in1) xa1 = *(const f32x4*)(xp1 + kn);
            wa0 = *(const f32x4*)(wp + kn);
            wa1 = *(const f32x4*)(wp + (size_t)64 * FEAT + kn);
            wa2 = *(const f32x4*)(wp + (size_t)128 * FEAT + kn);
            wa3 = *(const f32x4*)(wp + (size_t)192 * FEAT + kn);
        }
        {
            short8 a[4], b[4];
            #pragma unroll
            for (int i = 0; i < 4; ++i) a[i] = *(const short8*)&As[wr + i * 16 + r][kr];
            #pragma unroll
            for (int j = 0; j < 4; ++j) b[j] = *(const short8*)&Bs[wc + j * 16 + r][kr];
            #pragma unroll
            for (int i = 0; i < 4; ++i)
                #pragma unroll
                for (int j = 0; j < 4; ++j)
                    acc[i][j] = __builtin_amdgcn_mfma_f32_16x16x32_bf16(a[i], b[j], acc[i][j], 0, 0, 0);
        }

        // ---- substep B: stage k0+32 from set B ----
        __syncthreads();
        {
            uint2 u0 = {cvtpk(xb0.x, xb0.y), cvtpk(xb0.z, xb0.w)};
            uint2 u1 = {cvtpk(xb1.x, xb1.y), cvtpk(xb1.z, xb1.w)};
            *(uint2*)&As[srow][sc4]      = u0;
            *(uint2*)&As[srow + 64][sc4] = u1;
            uint2 w0 = {cvtpk(wb0.x, wb0.y), cvtpk(wb0.z, wb0.w)};
            uint2 w1 = {cvtpk(wb1.x, wb1.y), cvtpk(wb1.z, wb1.w)};
            uint2 w2 = {cvtpk(wb2.x, wb2.y), cvtpk(wb2.z, wb2.w)};
            uint2 w3 = {cvtpk(wb3.x, wb3.y), cvtpk(wb3.z, wb3.w)};
            *(uint2*)&Bs[srow][sc4]       = w0;
            *(uint2*)&Bs[srow + 64][sc4]  = w1;
            *(uint2*)&Bs[srow + 128][sc4] = w2;
            *(uint2*)&Bs[srow + 192][sc4] = w3;
        }
        __syncthreads();
        if (k0 + 96 < FEAT) {           // issue B <- k0+96 (2 steps ahead)
            const int kn = k0 + 96;
            xb0 = {0,0,0,0}; xb1 = {0,0,0,0};
            if (in0) xb0 = *(const f32x4*)(xp0 + kn);
            if (in1) xb1 = *(const f32x4*)(xp1 + kn);
            wb0 = *(const f32x4*)(wp + kn);
            wb1 = *(const f32x4*)(wp + (size_t)64 * FEAT + kn);
            wb2 = *(const f32x4*)(wp + (size_t)128 * FEAT + kn);
            wb3 = *(const f32x4*)(wp + (size_t)192 * FEAT + kn);
        }
        {
            short8 a[4], b[4];
            #pragma unroll
            for (int i = 0; i < 4; ++i) a[i] = *(const short8*)&As[wr + i * 16 + r][kr];
            #pragma unroll
            for (int j = 0; j < 4; ++j) b[j] = *(const short8*)&Bs[wc + j * 16 + r][kr];
            #pragma unroll
            for (int i = 0; i < 4; ++i)
                #pragma unroll
                for (int j = 0; j < 4; ++j)
                    acc[i][j] = __builtin_amdgcn_mfma_f32_16x16x32_bf16(a[i], b[j], acc[i][j], 0, 0, 0);
        }
    }

    // epilogue: C/D mapping col = wc + j*16 + (lane&15), row = wr + i*16 + (lane>>4)*4 + q.
    const int g  = lane >> 4;
    const int cc = lane & 15;
    const int b  = wave & 3;          // 64-col block index (= wc/64)
    #pragma unroll
    for (int i = 0; i < 4; ++i) {
        #pragma unroll
        for (int q = 0; q < 4; ++q) {
            const int row = m0 + wr + i * 16 + g * 4 + q;
            float mx = fmaxf(fmaxf(fabsf(acc[i][0][q]), fabsf(acc[i][1][q])),
                             fmaxf(fabsf(acc[i][2][q]), fabsf(acc[i][3][q])));
            mx = fmaxf(mx, __shfl_xor(mx, 1, 64));
            mx = fmaxf(mx, __shfl_xor(mx, 2, 64));
            mx = fmaxf(mx, __shfl_xor(mx, 4, 64));
            mx = fmaxf(mx, __shfl_xor(mx, 8, 64));
            const float inv = mx > 1e-30f ? 127.0f * __builtin_amdgcn_rcpf(mx) : 0.0f;
            if (row < M) {
                unsigned wdw = 0;
                #pragma unroll
                for (int j = 0; j < 4; ++j) {
                    int u = (int)fmaf(acc[i][j][q], inv, 128.5f);
                    u = u < 0 ? 0 : (u > 255 ? 255 : u);
                    wdw |= (unsigned)u << (8 * j);
                }
                H32[(size_t)row * 64 + b * 16 + cc] = wdw;
                if (cc == 0) S[(size_t)row * 4 + b] = mx * (1.0f / 127.0f);
            }
        }
    }
}

// edge_dst is sorted: rp[n] = first edge with dst >= n; rp[N] = E.
__global__ __launch_bounds__(256) void build_rowptr(
    const int* __restrict__ dst, int* __restrict__ rp, int E, int N) {
    int e = blockIdx.x * 256 + threadIdx.x;
    if (e >= E) return;
    int d    = dst[e];
    int prev = (e == 0) ? -1 : dst[e - 1];
    for (int n = prev + 1; n <= d; ++n) rp[n] = e;
    if (e == E - 1) {
        for (int n = d + 1; n <= N; ++n) rp[n] = E;
    }
}

// SpMM over int8 H (256B rows). 16-lane group per node (4 nodes/wave); lane
// owns 16 bytes (one uint4) of the row. Dual chains = 8 edges in flight/wave.
// Dequant bias-correction: out = sum(vs*u) - 128*sum(vs). NT stores.
// FROZEN: schedule variants (4-deep x2) neutral/worse; column-slicing
// catastrophic (FETCH 228MB -> 1.05GB: slice gathers still miss L2 and pay
// line-granularity 8x). Round-0 form = structural floor (FETCH at the
// random-gather limit, ~55% of logical bytes absorbed by L2/L3).
__global__ __launch_bounds__(256) void spmm_q8(
    const uint4* __restrict__ H16, const float* __restrict__ S,
    const int* __restrict__ rp, const int* __restrict__ src,
    const float* __restrict__ val, float* __restrict__ out, int M) {
    const int lane = threadIdx.x & 63;
    const int wave = threadIdx.x >> 6;
    const int li   = lane & 15;          // lane within group
    const int grp  = lane >> 4;          // group 0..3
    const int b    = li >> 2;            // 64-col block
    const int node = blockIdx.x * 16 + wave * 4 + grp;
    if (node >= M) return;
    const int lo = rp[node], hi = rp[node + 1];

    float a0[16], a1[16];                // k = d*4 + j
    #pragma unroll
    for (int k = 0; k < 16; ++k) { a0[k] = 0.f; a1[k] = 0.f; }
    float corr0 = 0.f, corr1 = 0.f;

    for (int e = lo; e < hi; e += 2) {
        const int e1 = e + 1;
        const int c1 = e1 < hi ? e1 : e;
        const int s0 = src[e], s1 = src[c1];
        const float v0 = val[e];
        float v1 = e1 < hi ? val[c1] : 0.f;
        const float vs0 = v0 * S[(size_t)s0 * 4 + b];
        const float vs1 = v1 * S[(size_t)s1 * 4 + b];
        const uint4 p0 = H16[(size_t)s0 * 16 + li];
        const uint4 p1 = H16[(size_t)s1 * 16 + li];
        corr0 += vs0;
        corr1 += vs1;
        const unsigned pd0[4] = {p0.x, p0.y, p0.z, p0.w};
        const unsigned pd1[4] = {p1.x, p1.y, p1.z, p1.w};
        #pragma unroll
        for (int d = 0; d < 4; ++d) {
            #pragma unroll
            for (int j = 0; j < 4; ++j) {
                a0[d * 4 + j] += vs0 * (float)((pd0[d] >> (8 * j)) & 0xffu);
                a1[d * 4 + j] += vs1 * (float)((pd1[d] >> (8 * j)) & 0xffu);
            }
        }
    }

    const float corr = (corr0 + corr1) * 128.0f;
    float* const obase = out + (size_t)node * EMB + b * 64 + (li & 3) * 4;
    #pragma unroll
    for (int j = 0; j < 4; ++j) {
        f32x4 o = {a0[j]      + a1[j]      - corr,
                   a0[4 + j]  + a1[4 + j]  - corr,
                   a0[8 + j]  + a1[8 + j]  - corr,
                   a0[12 + j] + a1[12 + j] - corr};
        __builtin_nontemporal_store(o, (f32x4*)(obase + j * 16));
    }
}

extern "C" void kernel_launch(void* const* d_in, const int* in_sizes, int n_in,
                              void* d_out, int out_size, void* d_ws, size_t ws_size,
                              hipStream_t stream) {
    const float* x    = (const float*)d_in[0];
    const float* w    = (const float*)d_in[1];
    const int*   esrc = (const int*)d_in[2];
    const int*   edst = (const int*)d_in[3];
    const float* eval = (const float*)d_in[4];

    const int M = in_sizes[0] / FEAT;   // 100000
    const int E = in_sizes[2];          // 1600000

    unsigned* Hbuf = (unsigned*)d_ws;                               // [M][64] dwords (int8 rows)
    float*    S    = (float*)((char*)d_ws + (size_t)M * 256);       // [M][4] scales
    int*      rp   = (int*)((char*)S + (size_t)M * 4 * sizeof(float));

    gemm_q8<<<(M + 127) / 128, 512, 0, stream>>>(x, w, Hbuf, S, M);
    build_rowptr<<<(E + 255) / 256, 256, 0, stream>>>(edst, rp, E, M);
    spmm_q8<<<(M + 15) / 16, 256, 0, stream>>>((const uint4*)Hbuf, S, rp, esrc, eval,
                                               (float*)d_out, M);
}